// Round 1
// baseline (3579.050 us; speedup 1.0000x reference)
//
#include <hip/hip_runtime.h>

#define D_FEAT 128
#define Q_PER_ROW 32   // 128 feats / 4 per float4

__global__ void accumulate_kernel(const float4* __restrict__ fine,
                                  const int* __restrict__ map,
                                  float* __restrict__ out_sum,
                                  float* __restrict__ counts,
                                  long long total /* n_fine * 32 */) {
    long long idx = (long long)blockIdx.x * blockDim.x + threadIdx.x;
    long long stride = (long long)gridDim.x * blockDim.x;
    for (; idx < total; idx += stride) {
        long long row = idx >> 5;
        int q = (int)(idx & 31);
        int seg = map[row];
        float4 v = fine[row * Q_PER_ROW + q];
        float* dst = out_sum + (long long)seg * D_FEAT + q * 4;
        atomicAdd(dst + 0, v.x);
        atomicAdd(dst + 1, v.y);
        atomicAdd(dst + 2, v.z);
        atomicAdd(dst + 3, v.w);
        if (q == 0) atomicAdd(&counts[seg], 1.0f);
    }
}

__global__ void finalize_kernel(float4* __restrict__ out,
                                const float* __restrict__ counts,
                                long long total /* m * 32 */) {
    long long idx = (long long)blockIdx.x * blockDim.x + threadIdx.x;
    long long stride = (long long)gridDim.x * blockDim.x;
    for (; idx < total; idx += stride) {
        int seg = (int)(idx >> 5);
        float c = counts[seg];
        float inv = (c > 0.0f) ? (1.0f / c) : 0.0f;
        float4 v = out[idx];
        v.x *= inv; v.y *= inv; v.z *= inv; v.w *= inv;
        out[idx] = v;
    }
}

extern "C" void kernel_launch(void* const* d_in, const int* in_sizes, int n_in,
                              void* d_out, int out_size, void* d_ws, size_t ws_size,
                              hipStream_t stream) {
    const float* fine = (const float*)d_in[0];
    const int* map = (const int*)d_in[1];
    float* out = (float*)d_out;
    float* counts = (float*)d_ws;

    long long n_fine = (long long)in_sizes[0] / D_FEAT;
    long long m = (long long)out_size / D_FEAT;

    // Zero sums (d_out) and counts (d_ws) — harness poisons with 0xAA.
    hipMemsetAsync(d_out, 0, (size_t)out_size * sizeof(float), stream);
    hipMemsetAsync(d_ws, 0, (size_t)m * sizeof(float), stream);

    long long total_acc = n_fine * Q_PER_ROW;      // 64M work items
    int block = 256;
    int grid_acc = 4096;                            // grid-stride
    accumulate_kernel<<<grid_acc, block, 0, stream>>>(
        (const float4*)fine, map, out, counts, total_acc);

    long long total_fin = m * Q_PER_ROW;            // 16M float4s
    int grid_fin = 2048;
    finalize_kernel<<<grid_fin, block, 0, stream>>>(
        (float4*)out, counts, total_fin);
}

// Round 2
// 707.372 us; speedup vs baseline: 5.0596x; 5.0596x over previous
//
#include <hip/hip_runtime.h>

#define D_FEAT 128

// ---------- Phase 1: histogram ----------
__global__ void count_kernel(const int* __restrict__ map, int* __restrict__ counts, int n) {
    int idx = blockIdx.x * blockDim.x + threadIdx.x;
    int stride = gridDim.x * blockDim.x;
    for (; idx < n; idx += stride) {
        atomicAdd(&counts[map[idx]], 1);
    }
}

// ---------- Phase 2a: per-tile exclusive scan (tile = 2048) ----------
__global__ void scan_partial_kernel(const int* __restrict__ counts,
                                    int* __restrict__ offsets,
                                    int* __restrict__ block_sums, int m) {
    __shared__ int sdata[256];
    const int tid = threadIdx.x;
    const int tile0 = blockIdx.x * 2048;
    int vals[8];
    int tsum = 0;
    #pragma unroll
    for (int j = 0; j < 8; ++j) {
        int idx = tile0 + tid * 8 + j;
        vals[j] = (idx < m) ? counts[idx] : 0;
        tsum += vals[j];
    }
    sdata[tid] = tsum;
    __syncthreads();
    // Hillis-Steele inclusive scan over 256 thread sums
    for (int off = 1; off < 256; off <<= 1) {
        int t = (tid >= off) ? sdata[tid - off] : 0;
        __syncthreads();
        sdata[tid] += t;
        __syncthreads();
    }
    int thread_excl = sdata[tid] - tsum;
    if (tid == 255) block_sums[blockIdx.x] = sdata[255];
    int run = thread_excl;
    #pragma unroll
    for (int j = 0; j < 8; ++j) {
        int idx = tile0 + tid * 8 + j;
        if (idx < m) offsets[idx] = run;
        run += vals[j];
    }
}

// ---------- Phase 2b: scan the per-tile sums (single block) ----------
__global__ void scan_block_sums_kernel(int* __restrict__ block_sums, int nb) {
    __shared__ int sdata[256];
    const int tid = threadIdx.x;
    int carry = 0;
    for (int base = 0; base < nb; base += 256) {
        int v = (base + tid < nb) ? block_sums[base + tid] : 0;
        sdata[tid] = v;
        __syncthreads();
        for (int off = 1; off < 256; off <<= 1) {
            int t = (tid >= off) ? sdata[tid - off] : 0;
            __syncthreads();
            sdata[tid] += t;
            __syncthreads();
        }
        int excl = sdata[tid] - v;
        if (base + tid < nb) block_sums[base + tid] = carry + excl;
        int total = sdata[255];
        __syncthreads();
        carry += total;
    }
}

// ---------- Phase 2c: finalize offsets, init cursors ----------
__global__ void add_block_offsets_kernel(int* __restrict__ offsets,
                                         int* __restrict__ cursors,
                                         const int* __restrict__ block_sums, int m) {
    int idx = blockIdx.x * blockDim.x + threadIdx.x;
    int stride = gridDim.x * blockDim.x;
    for (; idx < m; idx += stride) {
        int v = offsets[idx] + block_sums[idx >> 11];
        offsets[idx] = v;
        cursors[idx] = v;
    }
}

// ---------- Phase 3: scatter row ids (CSR fill) ----------
__global__ void scatter_kernel(const int* __restrict__ map,
                               int* __restrict__ cursors,
                               int* __restrict__ perm, int n) {
    int idx = blockIdx.x * blockDim.x + threadIdx.x;
    int stride = gridDim.x * blockDim.x;
    for (; idx < n; idx += stride) {
        int s = map[idx];
        int pos = atomicAdd(&cursors[s], 1);
        perm[pos] = idx;
    }
}

// ---------- Phase 4: gather + mean, one wave per segment ----------
__global__ void gather_mean_kernel(const float2* __restrict__ fine,
                                   const int* __restrict__ perm,
                                   const int* __restrict__ offsets,
                                   const int* __restrict__ counts,
                                   float2* __restrict__ out, int m) {
    int gwave = (blockIdx.x * blockDim.x + threadIdx.x) >> 6;
    int lane = threadIdx.x & 63;
    if (gwave >= m) return;
    int start = offsets[gwave];
    int cnt = counts[gwave];
    float ax = 0.0f, ay = 0.0f;
    for (int j = 0; j < cnt; ++j) {
        int row = perm[start + j];
        float2 v = fine[(long long)row * 64 + lane];
        ax += v.x;
        ay += v.y;
    }
    float inv = (cnt > 0) ? (1.0f / (float)cnt) : 0.0f;
    float2 r;
    r.x = ax * inv;
    r.y = ay * inv;
    out[(long long)gwave * 64 + lane] = r;
}

// ---------- Fallback (atomic scatter) if ws too small ----------
__global__ void accumulate_fallback(const float4* __restrict__ fine,
                                    const int* __restrict__ map,
                                    float* __restrict__ out_sum,
                                    float* __restrict__ counts,
                                    long long total) {
    long long idx = (long long)blockIdx.x * blockDim.x + threadIdx.x;
    long long stride = (long long)gridDim.x * blockDim.x;
    for (; idx < total; idx += stride) {
        long long row = idx >> 5;
        int q = (int)(idx & 31);
        int seg = map[row];
        float4 v = fine[row * 32 + q];
        float* dst = out_sum + (long long)seg * D_FEAT + q * 4;
        atomicAdd(dst + 0, v.x);
        atomicAdd(dst + 1, v.y);
        atomicAdd(dst + 2, v.z);
        atomicAdd(dst + 3, v.w);
        if (q == 0) atomicAdd(&counts[seg], 1.0f);
    }
}

__global__ void finalize_fallback(float4* __restrict__ out,
                                  const float* __restrict__ counts,
                                  long long total) {
    long long idx = (long long)blockIdx.x * blockDim.x + threadIdx.x;
    long long stride = (long long)gridDim.x * blockDim.x;
    for (; idx < total; idx += stride) {
        int seg = (int)(idx >> 5);
        float c = counts[seg];
        float inv = (c > 0.0f) ? (1.0f / c) : 0.0f;
        float4 v = out[idx];
        v.x *= inv; v.y *= inv; v.z *= inv; v.w *= inv;
        out[idx] = v;
    }
}

extern "C" void kernel_launch(void* const* d_in, const int* in_sizes, int n_in,
                              void* d_out, int out_size, void* d_ws, size_t ws_size,
                              hipStream_t stream) {
    const float* fine = (const float*)d_in[0];
    const int* map = (const int*)d_in[1];
    float* out = (float*)d_out;

    int n = in_sizes[1];                 // N_FINE
    int m = out_size / D_FEAT;           // N_COARSE
    int nb = (m + 2047) / 2048;          // scan tiles

    // Workspace layout (ints): counts[m], offsets[m], cursors[m], block_sums[pad], perm[n]
    int bs_pad = ((nb + 255) / 256) * 256;
    size_t need = ((size_t)3 * m + bs_pad + n) * sizeof(int);

    if (ws_size < need) {
        // Fallback: atomic accumulate (correct, slower)
        float* fcounts = (float*)d_ws;
        hipMemsetAsync(d_out, 0, (size_t)out_size * sizeof(float), stream);
        hipMemsetAsync(d_ws, 0, (size_t)m * sizeof(float), stream);
        accumulate_fallback<<<4096, 256, 0, stream>>>(
            (const float4*)fine, map, out, fcounts, (long long)n * 32);
        finalize_fallback<<<2048, 256, 0, stream>>>(
            (float4*)out, fcounts, (long long)m * 32);
        return;
    }

    int* counts = (int*)d_ws;
    int* offsets = counts + m;
    int* cursors = offsets + m;
    int* block_sums = cursors + m;
    int* perm = block_sums + bs_pad;

    hipMemsetAsync(counts, 0, (size_t)m * sizeof(int), stream);

    count_kernel<<<2048, 256, 0, stream>>>(map, counts, n);
    scan_partial_kernel<<<nb, 256, 0, stream>>>(counts, offsets, block_sums, m);
    scan_block_sums_kernel<<<1, 256, 0, stream>>>(block_sums, nb);
    add_block_offsets_kernel<<<2048, 256, 0, stream>>>(offsets, cursors, block_sums, m);
    scatter_kernel<<<2048, 256, 0, stream>>>(map, cursors, perm, n);

    // one wave (64 lanes) per segment; 4 waves per 256-thread block
    int nblocks = (m + 3) / 4;
    gather_mean_kernel<<<nblocks, 256, 0, stream>>>(
        (const float2*)fine, perm, offsets, counts, (float2*)out, m);
}

// Round 3
// 551.287 us; speedup vs baseline: 6.4922x; 1.2831x over previous
//
#include <hip/hip_runtime.h>

#define D_FEAT 128

// ---------- Phase 1: histogram ----------
__global__ void count_kernel(const int* __restrict__ map, int* __restrict__ counts, int n) {
    int idx = blockIdx.x * blockDim.x + threadIdx.x;
    int stride = gridDim.x * blockDim.x;
    for (; idx < n; idx += stride) {
        atomicAdd(&counts[map[idx]], 1);
    }
}

// ---------- Phase 2a: per-tile exclusive scan (tile = 2048) ----------
__global__ void scan_partial_kernel(const int* __restrict__ counts,
                                    int* __restrict__ offsets,
                                    int* __restrict__ block_sums, int m) {
    __shared__ int sdata[256];
    const int tid = threadIdx.x;
    const int tile0 = blockIdx.x * 2048;
    int vals[8];
    int tsum = 0;
    #pragma unroll
    for (int j = 0; j < 8; ++j) {
        int idx = tile0 + tid * 8 + j;
        vals[j] = (idx < m) ? counts[idx] : 0;
        tsum += vals[j];
    }
    sdata[tid] = tsum;
    __syncthreads();
    for (int off = 1; off < 256; off <<= 1) {
        int t = (tid >= off) ? sdata[tid - off] : 0;
        __syncthreads();
        sdata[tid] += t;
        __syncthreads();
    }
    int thread_excl = sdata[tid] - tsum;
    if (tid == 255) block_sums[blockIdx.x] = sdata[255];
    int run = thread_excl;
    #pragma unroll
    for (int j = 0; j < 8; ++j) {
        int idx = tile0 + tid * 8 + j;
        if (idx < m) offsets[idx] = run;
        run += vals[j];
    }
}

// ---------- Phase 2b: scan the per-tile sums (single block) ----------
__global__ void scan_block_sums_kernel(int* __restrict__ block_sums, int nb) {
    __shared__ int sdata[256];
    const int tid = threadIdx.x;
    int carry = 0;
    for (int base = 0; base < nb; base += 256) {
        int v = (base + tid < nb) ? block_sums[base + tid] : 0;
        sdata[tid] = v;
        __syncthreads();
        for (int off = 1; off < 256; off <<= 1) {
            int t = (tid >= off) ? sdata[tid - off] : 0;
            __syncthreads();
            sdata[tid] += t;
            __syncthreads();
        }
        int excl = sdata[tid] - v;
        if (base + tid < nb) block_sums[base + tid] = carry + excl;
        int total = sdata[255];
        __syncthreads();
        carry += total;
    }
}

// ---------- Phase 2c: finalize offsets, init cursors ----------
__global__ void add_block_offsets_kernel(int* __restrict__ offsets,
                                         int* __restrict__ cursors,
                                         const int* __restrict__ block_sums, int m) {
    int idx = blockIdx.x * blockDim.x + threadIdx.x;
    int stride = gridDim.x * blockDim.x;
    for (; idx < m; idx += stride) {
        int v = offsets[idx] + block_sums[idx >> 11];
        offsets[idx] = v;
        cursors[idx] = v;
    }
}

// ---------- Phase 3: scatter row ids (CSR fill) ----------
__global__ void scatter_kernel(const int* __restrict__ map,
                               int* __restrict__ cursors,
                               int* __restrict__ perm, int n) {
    int idx = blockIdx.x * blockDim.x + threadIdx.x;
    int stride = gridDim.x * blockDim.x;
    for (; idx < n; idx += stride) {
        int s = map[idx];
        int pos = atomicAdd(&cursors[s], 1);
        perm[pos] = idx;
    }
}

// ---------- Phase 4: gather + mean, one wave per segment, MLP-unrolled ----------
__global__ void gather_mean_kernel(const float2* __restrict__ fine,
                                   const int* __restrict__ perm,
                                   const int* __restrict__ offsets,
                                   const int* __restrict__ counts,
                                   float2* __restrict__ out, int m) {
    int gwave = (blockIdx.x * blockDim.x + threadIdx.x) >> 6;
    int lane = threadIdx.x & 63;
    if (gwave >= m) return;
    int start = offsets[gwave];
    int cnt = counts[gwave];

    float a0x = 0.f, a0y = 0.f, a1x = 0.f, a1y = 0.f;
    float a2x = 0.f, a2y = 0.f, a3x = 0.f, a3y = 0.f;

    int j = 0;
    // 4 independent row loads in flight per iteration
    for (; j + 4 <= cnt; j += 4) {
        int r0 = perm[start + j + 0];
        int r1 = perm[start + j + 1];
        int r2 = perm[start + j + 2];
        int r3 = perm[start + j + 3];
        float2 v0 = fine[(long long)r0 * 64 + lane];
        float2 v1 = fine[(long long)r1 * 64 + lane];
        float2 v2 = fine[(long long)r2 * 64 + lane];
        float2 v3 = fine[(long long)r3 * 64 + lane];
        a0x += v0.x; a0y += v0.y;
        a1x += v1.x; a1y += v1.y;
        a2x += v2.x; a2y += v2.y;
        a3x += v3.x; a3y += v3.y;
    }
    // tail: up to 3 rows, still independent
    if (j + 2 <= cnt) {
        int r0 = perm[start + j + 0];
        int r1 = perm[start + j + 1];
        float2 v0 = fine[(long long)r0 * 64 + lane];
        float2 v1 = fine[(long long)r1 * 64 + lane];
        a0x += v0.x; a0y += v0.y;
        a1x += v1.x; a1y += v1.y;
        j += 2;
    }
    if (j < cnt) {
        int r0 = perm[start + j];
        float2 v0 = fine[(long long)r0 * 64 + lane];
        a2x += v0.x; a2y += v0.y;
    }

    float sx = (a0x + a1x) + (a2x + a3x);
    float sy = (a0y + a1y) + (a2y + a3y);
    float inv = (cnt > 0) ? (1.0f / (float)cnt) : 0.0f;
    float2 r;
    r.x = sx * inv;
    r.y = sy * inv;
    out[(long long)gwave * 64 + lane] = r;
}

// ---------- Fallback (atomic scatter) if ws too small ----------
__global__ void accumulate_fallback(const float4* __restrict__ fine,
                                    const int* __restrict__ map,
                                    float* __restrict__ out_sum,
                                    float* __restrict__ counts,
                                    long long total) {
    long long idx = (long long)blockIdx.x * blockDim.x + threadIdx.x;
    long long stride = (long long)gridDim.x * blockDim.x;
    for (; idx < total; idx += stride) {
        long long row = idx >> 5;
        int q = (int)(idx & 31);
        int seg = map[row];
        float4 v = fine[row * 32 + q];
        float* dst = out_sum + (long long)seg * D_FEAT + q * 4;
        atomicAdd(dst + 0, v.x);
        atomicAdd(dst + 1, v.y);
        atomicAdd(dst + 2, v.z);
        atomicAdd(dst + 3, v.w);
        if (q == 0) atomicAdd(&counts[seg], 1.0f);
    }
}

__global__ void finalize_fallback(float4* __restrict__ out,
                                  const float* __restrict__ counts,
                                  long long total) {
    long long idx = (long long)blockIdx.x * blockDim.x + threadIdx.x;
    long long stride = (long long)gridDim.x * blockDim.x;
    for (; idx < total; idx += stride) {
        int seg = (int)(idx >> 5);
        float c = counts[seg];
        float inv = (c > 0.0f) ? (1.0f / c) : 0.0f;
        float4 v = out[idx];
        v.x *= inv; v.y *= inv; v.z *= inv; v.w *= inv;
        out[idx] = v;
    }
}

extern "C" void kernel_launch(void* const* d_in, const int* in_sizes, int n_in,
                              void* d_out, int out_size, void* d_ws, size_t ws_size,
                              hipStream_t stream) {
    const float* fine = (const float*)d_in[0];
    const int* map = (const int*)d_in[1];
    float* out = (float*)d_out;

    int n = in_sizes[1];                 // N_FINE
    int m = out_size / D_FEAT;           // N_COARSE
    int nb = (m + 2047) / 2048;          // scan tiles

    int bs_pad = ((nb + 255) / 256) * 256;
    size_t need = ((size_t)3 * m + bs_pad + n) * sizeof(int);

    if (ws_size < need) {
        float* fcounts = (float*)d_ws;
        hipMemsetAsync(d_out, 0, (size_t)out_size * sizeof(float), stream);
        hipMemsetAsync(d_ws, 0, (size_t)m * sizeof(float), stream);
        accumulate_fallback<<<4096, 256, 0, stream>>>(
            (const float4*)fine, map, out, fcounts, (long long)n * 32);
        finalize_fallback<<<2048, 256, 0, stream>>>(
            (float4*)out, fcounts, (long long)m * 32);
        return;
    }

    int* counts = (int*)d_ws;
    int* offsets = counts + m;
    int* cursors = offsets + m;
    int* block_sums = cursors + m;
    int* perm = block_sums + bs_pad;

    hipMemsetAsync(counts, 0, (size_t)m * sizeof(int), stream);

    count_kernel<<<2048, 256, 0, stream>>>(map, counts, n);
    scan_partial_kernel<<<nb, 256, 0, stream>>>(counts, offsets, block_sums, m);
    scan_block_sums_kernel<<<1, 256, 0, stream>>>(block_sums, nb);
    add_block_offsets_kernel<<<2048, 256, 0, stream>>>(offsets, cursors, block_sums, m);
    scatter_kernel<<<2048, 256, 0, stream>>>(map, cursors, perm, n);

    int nblocks = (m + 3) / 4;   // 4 waves (4 segments) per 256-thread block
    gather_mean_kernel<<<nblocks, 256, 0, stream>>>(
        (const float2*)fine, perm, offsets, counts, (float2*)out, m);
}

// Round 5
// 495.595 us; speedup vs baseline: 7.2217x; 1.1124x over previous
//
#include <hip/hip_runtime.h>

#define D_FEAT 128

typedef float f32x4 __attribute__((ext_vector_type(4)));

// ---------- Phase 1: histogram ----------
__global__ void count_kernel(const int* __restrict__ map, int* __restrict__ counts, int n) {
    int idx = blockIdx.x * blockDim.x + threadIdx.x;
    int stride = gridDim.x * blockDim.x;
    for (; idx < n; idx += stride) {
        atomicAdd(&counts[map[idx]], 1);
    }
}

// ---------- Phase 2a: per-tile exclusive scan (tile = 2048) ----------
__global__ void scan_partial_kernel(const int* __restrict__ counts,
                                    int* __restrict__ offsets,
                                    int* __restrict__ block_sums, int m) {
    __shared__ int sdata[256];
    const int tid = threadIdx.x;
    const int tile0 = blockIdx.x * 2048;
    int vals[8];
    int tsum = 0;
    #pragma unroll
    for (int j = 0; j < 8; ++j) {
        int idx = tile0 + tid * 8 + j;
        vals[j] = (idx < m) ? counts[idx] : 0;
        tsum += vals[j];
    }
    sdata[tid] = tsum;
    __syncthreads();
    for (int off = 1; off < 256; off <<= 1) {
        int t = (tid >= off) ? sdata[tid - off] : 0;
        __syncthreads();
        sdata[tid] += t;
        __syncthreads();
    }
    int thread_excl = sdata[tid] - tsum;
    if (tid == 255) block_sums[blockIdx.x] = sdata[255];
    int run = thread_excl;
    #pragma unroll
    for (int j = 0; j < 8; ++j) {
        int idx = tile0 + tid * 8 + j;
        if (idx < m) offsets[idx] = run;
        run += vals[j];
    }
}

// ---------- Phase 2b: scan the per-tile sums (single block) ----------
__global__ void scan_block_sums_kernel(int* __restrict__ block_sums, int nb) {
    __shared__ int sdata[256];
    const int tid = threadIdx.x;
    int carry = 0;
    for (int base = 0; base < nb; base += 256) {
        int v = (base + tid < nb) ? block_sums[base + tid] : 0;
        sdata[tid] = v;
        __syncthreads();
        for (int off = 1; off < 256; off <<= 1) {
            int t = (tid >= off) ? sdata[tid - off] : 0;
            __syncthreads();
            sdata[tid] += t;
            __syncthreads();
        }
        int excl = sdata[tid] - v;
        if (base + tid < nb) block_sums[base + tid] = carry + excl;
        int total = sdata[255];
        __syncthreads();
        carry += total;
    }
}

// ---------- Phase 2c: finalize offsets, init cursors ----------
__global__ void add_block_offsets_kernel(int* __restrict__ offsets,
                                         int* __restrict__ cursors,
                                         const int* __restrict__ block_sums, int m) {
    int idx = blockIdx.x * blockDim.x + threadIdx.x;
    int stride = gridDim.x * blockDim.x;
    for (; idx < m; idx += stride) {
        int v = offsets[idx] + block_sums[idx >> 11];
        offsets[idx] = v;
        cursors[idx] = v;
    }
}

// ---------- Phase 3: scatter row ids (CSR fill) ----------
__global__ void scatter_kernel(const int* __restrict__ map,
                               int* __restrict__ cursors,
                               int* __restrict__ perm, int n) {
    int idx = blockIdx.x * blockDim.x + threadIdx.x;
    int stride = gridDim.x * blockDim.x;
    for (; idx < n; idx += stride) {
        int s = map[idx];
        int pos = atomicAdd(&cursors[s], 1);
        perm[pos] = idx;
    }
}

// ---------- Phase 4: gather + mean ----------
// Half-wave (32 lanes) per segment, 16B loads: each load instruction
// covers 2 random 512B rows (1KB), 8 rows (4KB) in flight per wave.
__global__ void gather_mean_kernel(const f32x4* __restrict__ fine,
                                   const int* __restrict__ perm,
                                   const int* __restrict__ offsets,
                                   const int* __restrict__ counts,
                                   f32x4* __restrict__ out, int m) {
    int wid = (blockIdx.x * blockDim.x + threadIdx.x) >> 6;
    int lane = threadIdx.x & 63;
    int half = lane >> 5;
    int sl = lane & 31;
    int seg = wid * 2 + half;
    if (seg >= m) return;
    int start = offsets[seg];
    int cnt = counts[seg];

    f32x4 a0 = {0.f,0.f,0.f,0.f}, a1 = {0.f,0.f,0.f,0.f};
    f32x4 a2 = {0.f,0.f,0.f,0.f}, a3 = {0.f,0.f,0.f,0.f};

    int j = 0;
    for (; j + 4 <= cnt; j += 4) {
        int r0 = perm[start + j + 0];
        int r1 = perm[start + j + 1];
        int r2 = perm[start + j + 2];
        int r3 = perm[start + j + 3];
        f32x4 v0 = __builtin_nontemporal_load(&fine[(long long)r0 * 32 + sl]);
        f32x4 v1 = __builtin_nontemporal_load(&fine[(long long)r1 * 32 + sl]);
        f32x4 v2 = __builtin_nontemporal_load(&fine[(long long)r2 * 32 + sl]);
        f32x4 v3 = __builtin_nontemporal_load(&fine[(long long)r3 * 32 + sl]);
        a0 += v0;
        a1 += v1;
        a2 += v2;
        a3 += v3;
    }
    if (j + 2 <= cnt) {
        int r0 = perm[start + j + 0];
        int r1 = perm[start + j + 1];
        f32x4 v0 = __builtin_nontemporal_load(&fine[(long long)r0 * 32 + sl]);
        f32x4 v1 = __builtin_nontemporal_load(&fine[(long long)r1 * 32 + sl]);
        a0 += v0;
        a1 += v1;
        j += 2;
    }
    if (j < cnt) {
        int r0 = perm[start + j];
        f32x4 v0 = __builtin_nontemporal_load(&fine[(long long)r0 * 32 + sl]);
        a2 += v0;
    }

    float inv = (cnt > 0) ? (1.0f / (float)cnt) : 0.0f;
    f32x4 r = ((a0 + a1) + (a2 + a3)) * inv;
    __builtin_nontemporal_store(r, &out[(long long)seg * 32 + sl]);
}

// ---------- Fallback (atomic scatter) if ws too small ----------
__global__ void accumulate_fallback(const float4* __restrict__ fine,
                                    const int* __restrict__ map,
                                    float* __restrict__ out_sum,
                                    float* __restrict__ counts,
                                    long long total) {
    long long idx = (long long)blockIdx.x * blockDim.x + threadIdx.x;
    long long stride = (long long)gridDim.x * blockDim.x;
    for (; idx < total; idx += stride) {
        long long row = idx >> 5;
        int q = (int)(idx & 31);
        int seg = map[row];
        float4 v = fine[row * 32 + q];
        float* dst = out_sum + (long long)seg * D_FEAT + q * 4;
        atomicAdd(dst + 0, v.x);
        atomicAdd(dst + 1, v.y);
        atomicAdd(dst + 2, v.z);
        atomicAdd(dst + 3, v.w);
        if (q == 0) atomicAdd(&counts[seg], 1.0f);
    }
}

__global__ void finalize_fallback(float4* __restrict__ out,
                                  const float* __restrict__ counts,
                                  long long total) {
    long long idx = (long long)blockIdx.x * blockDim.x + threadIdx.x;
    long long stride = (long long)gridDim.x * blockDim.x;
    for (; idx < total; idx += stride) {
        int seg = (int)(idx >> 5);
        float c = counts[seg];
        float inv = (c > 0.0f) ? (1.0f / c) : 0.0f;
        float4 v = out[idx];
        v.x *= inv; v.y *= inv; v.z *= inv; v.w *= inv;
        out[idx] = v;
    }
}

extern "C" void kernel_launch(void* const* d_in, const int* in_sizes, int n_in,
                              void* d_out, int out_size, void* d_ws, size_t ws_size,
                              hipStream_t stream) {
    const float* fine = (const float*)d_in[0];
    const int* map = (const int*)d_in[1];
    float* out = (float*)d_out;

    int n = in_sizes[1];                 // N_FINE
    int m = out_size / D_FEAT;           // N_COARSE
    int nb = (m + 2047) / 2048;          // scan tiles

    int bs_pad = ((nb + 255) / 256) * 256;
    size_t need = ((size_t)3 * m + bs_pad + n) * sizeof(int);

    if (ws_size < need) {
        float* fcounts = (float*)d_ws;
        (void)hipMemsetAsync(d_out, 0, (size_t)out_size * sizeof(float), stream);
        (void)hipMemsetAsync(d_ws, 0, (size_t)m * sizeof(float), stream);
        accumulate_fallback<<<4096, 256, 0, stream>>>(
            (const float4*)fine, map, out, fcounts, (long long)n * 32);
        finalize_fallback<<<2048, 256, 0, stream>>>(
            (float4*)out, fcounts, (long long)m * 32);
        return;
    }

    int* counts = (int*)d_ws;
    int* offsets = counts + m;
    int* cursors = offsets + m;
    int* block_sums = cursors + m;
    int* perm = block_sums + bs_pad;

    (void)hipMemsetAsync(counts, 0, (size_t)m * sizeof(int), stream);

    count_kernel<<<2048, 256, 0, stream>>>(map, counts, n);
    scan_partial_kernel<<<nb, 256, 0, stream>>>(counts, offsets, block_sums, m);
    scan_block_sums_kernel<<<1, 256, 0, stream>>>(block_sums, nb);
    add_block_offsets_kernel<<<2048, 256, 0, stream>>>(offsets, cursors, block_sums, m);
    scatter_kernel<<<2048, 256, 0, stream>>>(map, cursors, perm, n);

    // one wave handles 2 adjacent segments (half-wave each)
    int nwaves = (m + 1) / 2;
    int nblocks = (nwaves + 3) / 4;      // 4 waves per 256-thread block
    gather_mean_kernel<<<nblocks, 256, 0, stream>>>(
        (const f32x4*)fine, perm, offsets, counts, (f32x4*)out, m);
}

// Round 6
// 493.626 us; speedup vs baseline: 7.2505x; 1.0040x over previous
//
#include <hip/hip_runtime.h>

#define D_FEAT 128

typedef float f32x4 __attribute__((ext_vector_type(4)));

// ---------- Phase 1: histogram ----------
__global__ void count_kernel(const int* __restrict__ map, int* __restrict__ counts, int n) {
    int idx = blockIdx.x * blockDim.x + threadIdx.x;
    int stride = gridDim.x * blockDim.x;
    for (; idx < n; idx += stride) {
        atomicAdd(&counts[map[idx]], 1);
    }
}

// ---------- Phase 2a: per-tile exclusive scan (tile = 2048) ----------
__global__ void scan_partial_kernel(const int* __restrict__ counts,
                                    int* __restrict__ offsets,
                                    int* __restrict__ block_sums, int m) {
    __shared__ int sdata[256];
    const int tid = threadIdx.x;
    const int tile0 = blockIdx.x * 2048;
    int vals[8];
    int tsum = 0;
    #pragma unroll
    for (int j = 0; j < 8; ++j) {
        int idx = tile0 + tid * 8 + j;
        vals[j] = (idx < m) ? counts[idx] : 0;
        tsum += vals[j];
    }
    sdata[tid] = tsum;
    __syncthreads();
    for (int off = 1; off < 256; off <<= 1) {
        int t = (tid >= off) ? sdata[tid - off] : 0;
        __syncthreads();
        sdata[tid] += t;
        __syncthreads();
    }
    int thread_excl = sdata[tid] - tsum;
    if (tid == 255) block_sums[blockIdx.x] = sdata[255];
    int run = thread_excl;
    #pragma unroll
    for (int j = 0; j < 8; ++j) {
        int idx = tile0 + tid * 8 + j;
        if (idx < m) offsets[idx] = run;
        run += vals[j];
    }
}

// ---------- Phase 2b: scan the per-tile sums (single block) ----------
__global__ void scan_block_sums_kernel(int* __restrict__ block_sums, int nb) {
    __shared__ int sdata[256];
    const int tid = threadIdx.x;
    int carry = 0;
    for (int base = 0; base < nb; base += 256) {
        int v = (base + tid < nb) ? block_sums[base + tid] : 0;
        sdata[tid] = v;
        __syncthreads();
        for (int off = 1; off < 256; off <<= 1) {
            int t = (tid >= off) ? sdata[tid - off] : 0;
            __syncthreads();
            sdata[tid] += t;
            __syncthreads();
        }
        int excl = sdata[tid] - v;
        if (base + tid < nb) block_sums[base + tid] = carry + excl;
        int total = sdata[255];
        __syncthreads();
        carry += total;
    }
}

// ---------- Phase 2c: finalize offsets, init cursors ----------
__global__ void add_block_offsets_kernel(int* __restrict__ offsets,
                                         int* __restrict__ cursors,
                                         const int* __restrict__ block_sums, int m) {
    int idx = blockIdx.x * blockDim.x + threadIdx.x;
    int stride = gridDim.x * blockDim.x;
    for (; idx < m; idx += stride) {
        int v = offsets[idx] + block_sums[idx >> 11];
        offsets[idx] = v;
        cursors[idx] = v;
    }
}

// ---------- Phase 3: scatter row ids (CSR fill) ----------
__global__ void scatter_kernel(const int* __restrict__ map,
                               int* __restrict__ cursors,
                               int* __restrict__ perm, int n) {
    int idx = blockIdx.x * blockDim.x + threadIdx.x;
    int stride = gridDim.x * blockDim.x;
    for (; idx < n; idx += stride) {
        int s = map[idx];
        int pos = atomicAdd(&cursors[s], 1);
        perm[pos] = idx;
    }
}

// ---------- Phase 4: gather + mean ----------
// Quarter-wave (16 lanes) per segment; each lane covers 32B of the 512B row
// (two f32x4 loads). Per wave: 4 segments x 4 rows x 512B = 8KB in flight.
__global__ void gather_mean_kernel(const f32x4* __restrict__ fine,
                                   const int* __restrict__ perm,
                                   const int* __restrict__ offsets,
                                   f32x4* __restrict__ out, int m, int n) {
    int wid = (blockIdx.x * blockDim.x + threadIdx.x) >> 6;
    int lane = threadIdx.x & 63;
    int q = lane >> 4;       // quarter 0..3
    int sl = lane & 15;      // lane within quarter
    int seg = wid * 4 + q;
    if (seg >= m) return;
    int start = offsets[seg];
    int end = (seg + 1 < m) ? offsets[seg + 1] : n;
    int cnt = end - start;

    f32x4 aL0 = {0,0,0,0}, aH0 = {0,0,0,0};
    f32x4 aL1 = {0,0,0,0}, aH1 = {0,0,0,0};
    f32x4 aL2 = {0,0,0,0}, aH2 = {0,0,0,0};
    f32x4 aL3 = {0,0,0,0}, aH3 = {0,0,0,0};

    int j = 0;
    for (; j + 4 <= cnt; j += 4) {
        int r0 = perm[start + j + 0];
        int r1 = perm[start + j + 1];
        int r2 = perm[start + j + 2];
        int r3 = perm[start + j + 3];
        const f32x4* p0 = &fine[(long long)r0 * 32 + sl];
        const f32x4* p1 = &fine[(long long)r1 * 32 + sl];
        const f32x4* p2 = &fine[(long long)r2 * 32 + sl];
        const f32x4* p3 = &fine[(long long)r3 * 32 + sl];
        f32x4 vL0 = __builtin_nontemporal_load(p0);
        f32x4 vH0 = __builtin_nontemporal_load(p0 + 16);
        f32x4 vL1 = __builtin_nontemporal_load(p1);
        f32x4 vH1 = __builtin_nontemporal_load(p1 + 16);
        f32x4 vL2 = __builtin_nontemporal_load(p2);
        f32x4 vH2 = __builtin_nontemporal_load(p2 + 16);
        f32x4 vL3 = __builtin_nontemporal_load(p3);
        f32x4 vH3 = __builtin_nontemporal_load(p3 + 16);
        aL0 += vL0; aH0 += vH0;
        aL1 += vL1; aH1 += vH1;
        aL2 += vL2; aH2 += vH2;
        aL3 += vL3; aH3 += vH3;
    }
    // masked tail: up to 3 rows, independent slots
    if (j + 0 < cnt) {
        int r = perm[start + j + 0];
        const f32x4* p = &fine[(long long)r * 32 + sl];
        aL0 += __builtin_nontemporal_load(p);
        aH0 += __builtin_nontemporal_load(p + 16);
    }
    if (j + 1 < cnt) {
        int r = perm[start + j + 1];
        const f32x4* p = &fine[(long long)r * 32 + sl];
        aL1 += __builtin_nontemporal_load(p);
        aH1 += __builtin_nontemporal_load(p + 16);
    }
    if (j + 2 < cnt) {
        int r = perm[start + j + 2];
        const f32x4* p = &fine[(long long)r * 32 + sl];
        aL2 += __builtin_nontemporal_load(p);
        aH2 += __builtin_nontemporal_load(p + 16);
    }

    float inv = (cnt > 0) ? (1.0f / (float)cnt) : 0.0f;
    f32x4 rL = ((aL0 + aL1) + (aL2 + aL3)) * inv;
    f32x4 rH = ((aH0 + aH1) + (aH2 + aH3)) * inv;
    f32x4* po = &out[(long long)seg * 32 + sl];
    __builtin_nontemporal_store(rL, po);
    __builtin_nontemporal_store(rH, po + 16);
}

// ---------- Fallback (atomic scatter) if ws too small ----------
__global__ void accumulate_fallback(const float4* __restrict__ fine,
                                    const int* __restrict__ map,
                                    float* __restrict__ out_sum,
                                    float* __restrict__ counts,
                                    long long total) {
    long long idx = (long long)blockIdx.x * blockDim.x + threadIdx.x;
    long long stride = (long long)gridDim.x * blockDim.x;
    for (; idx < total; idx += stride) {
        long long row = idx >> 5;
        int q = (int)(idx & 31);
        int seg = map[row];
        float4 v = fine[row * 32 + q];
        float* dst = out_sum + (long long)seg * D_FEAT + q * 4;
        atomicAdd(dst + 0, v.x);
        atomicAdd(dst + 1, v.y);
        atomicAdd(dst + 2, v.z);
        atomicAdd(dst + 3, v.w);
        if (q == 0) atomicAdd(&counts[seg], 1.0f);
    }
}

__global__ void finalize_fallback(float4* __restrict__ out,
                                  const float* __restrict__ counts,
                                  long long total) {
    long long idx = (long long)blockIdx.x * blockDim.x + threadIdx.x;
    long long stride = (long long)gridDim.x * blockDim.x;
    for (; idx < total; idx += stride) {
        int seg = (int)(idx >> 5);
        float c = counts[seg];
        float inv = (c > 0.0f) ? (1.0f / c) : 0.0f;
        float4 v = out[idx];
        v.x *= inv; v.y *= inv; v.z *= inv; v.w *= inv;
        out[idx] = v;
    }
}

extern "C" void kernel_launch(void* const* d_in, const int* in_sizes, int n_in,
                              void* d_out, int out_size, void* d_ws, size_t ws_size,
                              hipStream_t stream) {
    const float* fine = (const float*)d_in[0];
    const int* map = (const int*)d_in[1];
    float* out = (float*)d_out;

    int n = in_sizes[1];                 // N_FINE
    int m = out_size / D_FEAT;           // N_COARSE
    int nb = (m + 2047) / 2048;          // scan tiles

    int bs_pad = ((nb + 255) / 256) * 256;
    size_t need = ((size_t)3 * m + bs_pad + n) * sizeof(int);

    if (ws_size < need) {
        float* fcounts = (float*)d_ws;
        (void)hipMemsetAsync(d_out, 0, (size_t)out_size * sizeof(float), stream);
        (void)hipMemsetAsync(d_ws, 0, (size_t)m * sizeof(float), stream);
        accumulate_fallback<<<4096, 256, 0, stream>>>(
            (const float4*)fine, map, out, fcounts, (long long)n * 32);
        finalize_fallback<<<2048, 256, 0, stream>>>(
            (float4*)out, fcounts, (long long)m * 32);
        return;
    }

    int* counts = (int*)d_ws;
    int* offsets = counts + m;
    int* cursors = offsets + m;
    int* block_sums = cursors + m;
    int* perm = block_sums + bs_pad;

    (void)hipMemsetAsync(counts, 0, (size_t)m * sizeof(int), stream);

    count_kernel<<<2048, 256, 0, stream>>>(map, counts, n);
    scan_partial_kernel<<<nb, 256, 0, stream>>>(counts, offsets, block_sums, m);
    scan_block_sums_kernel<<<1, 256, 0, stream>>>(block_sums, nb);
    add_block_offsets_kernel<<<2048, 256, 0, stream>>>(offsets, cursors, block_sums, m);
    scatter_kernel<<<2048, 256, 0, stream>>>(map, cursors, perm, n);

    // one wave handles 4 adjacent segments (quarter-wave each)
    int nwaves = (m + 3) / 4;
    int nblocks = (nwaves + 3) / 4;      // 4 waves per 256-thread block
    gather_mean_kernel<<<nblocks, 256, 0, stream>>>(
        (const f32x4*)fine, perm, offsets, (f32x4*)out, m, n);
}